// Round 3
// baseline (9858.624 us; speedup 1.0000x reference)
//
#include <hip/hip_runtime.h>
#include <stdint.h>

#define NTT   365
#define NGRID 2048

typedef __attribute__((ext_vector_type(8))) short bf16x8;
typedef __attribute__((ext_vector_type(4))) float f32x4;

// LDS layout (byte offsets).
// Fragment = 16 rows x 32 K bf16 = 1024 B; lane slot l holds
// (row = l&15, k = (l>>4)*8 + e), e in [0,8) -> one ds_read_b128 per B-frag.
#define HF_OFF   0        // h_t frags: 8 x 1024 B
#define X0_OFF   8192     // x0 double buffer: 2 x 8 x 1024 B
#define XIN_OFF  24576    // x-input frag double buffer: 2 x 1024 B
#define POUT_OFF 26624    // out-proj partials: 16 waves x 16 rows f32
#define SMEM_BYTES 27648

__device__ __forceinline__ unsigned short f2bf(float f) {
  unsigned u = __builtin_bit_cast(unsigned, f);
  return (unsigned short)((u + 0x7FFFu + ((u >> 16) & 1u)) >> 16);  // RNE
}
__device__ __forceinline__ float sigm(float x) {
  return 1.0f / (1.0f + exp2f(-1.4426950408889634f * x));
}
__device__ __forceinline__ float tanh_f(float x) {
  return 2.0f / (1.0f + exp2f(-2.8853900817779268f * x)) - 1.0f;
}
__device__ __forceinline__ bf16x8 pack8(float4 a, float4 b) {
  bf16x8 r;
  r[0] = (short)f2bf(a.x); r[1] = (short)f2bf(a.y);
  r[2] = (short)f2bf(a.z); r[3] = (short)f2bf(a.w);
  r[4] = (short)f2bf(b.x); r[5] = (short)f2bf(b.y);
  r[6] = (short)f2bf(b.z); r[7] = (short)f2bf(b.w);
  return r;
}

// Fully block-local fused LSTM: 128 blocks x 16 batch rows, 16 waves/block.
// Wave w owns h-cols [16w,16w+16) -> 64 gate rows; weights (64 gate-rows x
// K=512 bf16) resident in VGPRs. Gates computed TRANSPOSED (verified r1/r2
// mapping): A-frag row G=16i+l15 -> gc=(G&3)*256+16w+(G>>2); D: col=l15=batch
// row, reg r = gate r for hcol 16w+4i+l4. h exchanged via LDS frags only.
extern "C" __global__ void __launch_bounds__(1024, 4)
kuai_lstm(const float* __restrict__ x, const float* __restrict__ w_in,
          const float* __restrict__ b_in, const float* __restrict__ w_ih,
          const float* __restrict__ w_hh, const float* __restrict__ b_ih,
          const float* __restrict__ b_hh, const float* __restrict__ w_out,
          const float* __restrict__ b_out, float* __restrict__ out) {
  __shared__ char smem[SMEM_BYTES];
  const int tid = threadIdx.x;
  const int l   = tid & 63;
  const int l15 = l & 15;
  const int l4  = l >> 4;
  const int w   = tid >> 6;          // wave 0..15
  const int r0  = blockIdx.x << 4;   // batch-row base

  // ---------------- prologue: weights -> VGPRs ----------------
  bf16x8 Wf[4][16];  // [gate-row tile i][K-chunk]; kc<8 = h-side, kc>=8 = x0-side
#pragma unroll
  for (int i = 0; i < 4; ++i) {
    const int G  = 16 * i + l15;
    const int gc = (G & 3) * 256 + 16 * w + (G >> 2);
    const float* bh = w_hh + (size_t)gc * 256;
    const float* bi = w_ih + (size_t)gc * 256;
#pragma unroll
    for (int kc = 0; kc < 16; ++kc) {
      const float* p = (kc < 8) ? (bh + kc * 32 + l4 * 8)
                                : (bi + (kc - 8) * 32 + l4 * 8);
      Wf[i][kc] = pack8(*(const float4*)p, *(const float4*)(p + 4));
    }
  }
  bf16x8 WinF;
  {
    const float* p = w_in + (size_t)(16 * w + l15) * 32 + l4 * 8;
    WinF = pack8(*(const float4*)p, *(const float4*)(p + 4));
  }
  float binv[4], bsv[4][4], wov[4];
#pragma unroll
  for (int r = 0; r < 4; ++r) binv[r] = b_in[16 * w + 4 * l4 + r];
#pragma unroll
  for (int i = 0; i < 4; ++i) {
    const int hc = 16 * w + 4 * i + l4;
    wov[i] = w_out[hc];
#pragma unroll
    for (int r = 0; r < 4; ++r) bsv[i][r] = b_ih[r * 256 + hc] + b_hh[r * 256 + hc];
  }
  const float b_out_v = b_out[0];
  float creg[4] = {0.f, 0.f, 0.f, 0.f};

  // stage raw x(tt) tile (16 rows x 32 f32 -> bf16 frag), wave 0 only
  auto stage_xin = [&](int tt) {
    const float* xp = x + ((size_t)tt * NGRID + r0 + l15) * 32 + l4 * 8;
    bf16x8 v = pack8(*(const float4*)xp, *(const float4*)(xp + 4));
    *(bf16x8*)(smem + XIN_OFF + (tt & 1) * 1024 + l * 16) = v;
  };
  // x0(tt) = relu(x_tt @ w_in^T + b_in): wave w produces cols [16w,16w+16)
  auto xphase = [&](int tt) {
    bf16x8 xf = *(const bf16x8*)(smem + XIN_OFF + (tt & 1) * 1024 + l * 16);
    f32x4 a;
    a[0] = binv[0]; a[1] = binv[1]; a[2] = binv[2]; a[3] = binv[3];
    a = __builtin_amdgcn_mfma_f32_16x16x32_bf16(WinF, xf, a, 0, 0, 0);
    char* xb = smem + X0_OFF + (tt & 1) * 8192 + (w >> 1) * 1024;
#pragma unroll
    for (int r = 0; r < 4; ++r) {
      int kk  = 16 * (w & 1) + 4 * l4 + r;           // k within 32-chunk
      int byt = ((kk >> 3) * 16 + l15) * 16 + (kk & 7) * 2;
      *(unsigned short*)(xb + byt) = f2bf(fmaxf(a[r], 0.f));
    }
  };

  if (w == 0) stage_xin(0);
  __syncthreads();
  xphase(0);
  if (w == 0) stage_xin(1);
  __syncthreads();

  // ---------------- time loop ----------------
  for (int t = 0; t < NTT; ++t) {
    const int p = t & 1;
    f32x4 acc[4];
#pragma unroll
    for (int i = 0; i < 4; ++i) {
      acc[i][0] = bsv[i][0]; acc[i][1] = bsv[i][1];
      acc[i][2] = bsv[i][2]; acc[i][3] = bsv[i][3];
    }
    // x0 half of K
    const char* xb = smem + X0_OFF + p * 8192;
#pragma unroll
    for (int c = 0; c < 8; ++c) {
      bf16x8 bf = *(const bf16x8*)(xb + c * 1024 + l * 16);
#pragma unroll
      for (int i = 0; i < 4; ++i)
        acc[i] = __builtin_amdgcn_mfma_f32_16x16x32_bf16(Wf[i][c + 8], bf, acc[i], 0, 0, 0);
    }
    // h half of K (h0 = 0 -> skip at t==0)
    if (t > 0) {
#pragma unroll
      for (int c = 0; c < 8; ++c) {
        bf16x8 hf = *(const bf16x8*)(smem + HF_OFF + c * 1024 + l * 16);
#pragma unroll
        for (int i = 0; i < 4; ++i)
          acc[i] = __builtin_amdgcn_mfma_f32_16x16x32_bf16(Wf[i][c], hf, acc[i], 0, 0, 0);
      }
    }
    // produce x0 for t+1 (reads xin staged 2 steps ago; different X0 buffer)
    if (t + 1 < NTT) xphase(t + 1);

    // nonlinearities (acc[i] regs 0..3 = i,f,g,o) + out-proj partial
    float hreg[4], s = 0.f;
#pragma unroll
    for (int i = 0; i < 4; ++i) {
      float gi = acc[i][0], gf = acc[i][1], gg = acc[i][2], go = acc[i][3];
      float cn = sigm(gf) * creg[i] + sigm(gi) * tanh_f(gg);
      float hn = sigm(go) * tanh_f(cn);
      creg[i] = cn;
      hreg[i] = hn;
      s += hn * wov[i];
    }
    s += __shfl_xor(s, 16);
    s += __shfl_xor(s, 32);   // lanes<16 hold row partial over this wave's 16 cols

    __syncthreads();  // all frag reads of this step done
    // write h_t frags (wave w -> k-chunk w>>1, sub-offset by w&1)
#pragma unroll
    for (int i = 0; i < 4; ++i) {
      int kk  = 16 * (w & 1) + 4 * i + l4;
      int byt = (w >> 1) * 1024 + ((kk >> 3) * 16 + l15) * 16 + (kk & 7) * 2;
      *(unsigned short*)(smem + HF_OFF + byt) = f2bf(hreg[i]);
    }
    if (l < 16) *(float*)(smem + POUT_OFF + w * 64 + l * 4) = s;
    if (w == 0 && t + 2 < NTT) stage_xin(t + 2);
    __syncthreads();  // h_t + pout visible
    if (w == 15 && l < 16) {
      float r = b_out_v;
#pragma unroll
      for (int j = 0; j < 16; ++j)
        r += *(const float*)(smem + POUT_OFF + j * 64 + l * 4);
      out[(size_t)t * NGRID + r0 + l] = r;
    }
  }
}

extern "C" void kernel_launch(void* const* d_in, const int* in_sizes, int n_in,
                              void* d_out, int out_size, void* d_ws, size_t ws_size,
                              hipStream_t stream) {
  (void)in_sizes; (void)n_in; (void)out_size; (void)d_ws; (void)ws_size;
  const float* x     = (const float*)d_in[0];
  const float* w_in  = (const float*)d_in[1];
  const float* b_in  = (const float*)d_in[2];
  const float* w_ih  = (const float*)d_in[3];
  const float* w_hh  = (const float*)d_in[4];
  const float* b_ih  = (const float*)d_in[5];
  const float* b_hh  = (const float*)d_in[6];
  const float* w_out = (const float*)d_in[7];
  const float* b_out = (const float*)d_in[8];
  float* out = (float*)d_out;

  hipLaunchKernelGGL(kuai_lstm, dim3(NGRID / 16), dim3(1024), 0, stream,
                     x, w_in, b_in, w_ih, w_hh, b_ih, b_hh, w_out, b_out, out);
}